// Round 10
// baseline (422.219 us; speedup 1.0000x reference)
//
#include <hip/hip_runtime.h>
#include <hip/hip_bf16.h>

typedef __attribute__((ext_vector_type(4))) float f32x4;
typedef __attribute__((ext_vector_type(8))) short bf16x8;

#define BM 256
#define BN 256
#define BK 32
#define KDIM 512
#define NT 16   // 512/32 K-tiles

// fp32 -> packed 2x bf16 (RNE); compiler emits v_cvt_pk_bf16_f32.
__device__ __forceinline__ unsigned int bfpack(float a, float b) {
  __hip_bfloat162 h = __float22bfloat162_rn(float2{a, b});
  union { __hip_bfloat162 h2; unsigned int u; } c;
  c.h2 = h;
  return c.u;
}

__device__ __forceinline__ bf16x8 cvt8(const f32x4 lo, const f32x4 hi) {
  union { bf16x8 v; unsigned int u[4]; } r;
  r.u[0] = bfpack(lo[0], lo[1]);
  r.u[1] = bfpack(lo[2], lo[3]);
  r.u[2] = bfpack(hi[0], hi[1]);
  r.u[3] = bfpack(hi[2], hi[3]);
  return r.v;
}

typedef __attribute__((address_space(1))) const unsigned int gas_u32;
typedef __attribute__((address_space(3))) unsigned int las_u32;

// Direct global->LDS DMA, 16B/lane: LDS dest = uniform base + lane*16.
__device__ __forceinline__ void gload16(const float* g, float* l) {
  __builtin_amdgcn_global_load_lds((gas_u32*)(const void*)g, (las_u32*)(void*)l, 16, 0, 0);
}

// fp32 tile rows are 128B = 8 x 16B granules. LDS granule (r, g) holds
// global granule g ^ (r&7)  (swizzle applied on the DMA *source*; DMA dest
// stays linear). Consume reads granule pair {q2^(r&7), (q2+1)^(r&7)}:
// per b128 wave-instruction each 4-bank group gets exactly 8 lanes =
// structural minimum -> conflict-free.
__launch_bounds__(512, 1)
__global__ void moe_grouped_gemm(const float* __restrict__ A,
                                 const float* __restrict__ W,
                                 float* __restrict__ C) {
  // 2 buffers x (256x32 A + 256x32 W) fp32 = 128 KiB LDS.
  __shared__ float As[2][BM * BK];
  __shared__ float Ws[2][BN * BK];

  const int tid  = threadIdx.x;
  const int lane = tid & 63;
  const int wid  = tid >> 6;     // 8 waves, 2 x 4; wave tile 128 x 64
  const int wm   = wid >> 2;     // 0..1
  const int wn   = wid & 3;      // 0..3

  // XCD map (m157 evidence: round-robin): e = b&7 pins expert to XCD;
  // blocks b, b+8 are (mt, nt=0/1) of the same expert -> share A-panel in L2.
  const int b  = blockIdx.x;
  const int e  = b & 7;
  const int tt = b >> 3;         // 0..255
  const int mt = tt >> 1;        // 128 m-tiles
  const int nt = tt & 1;         // 2 n-tiles

  const size_t mBase = (size_t)e * 32768 + (size_t)mt * BM;
  const int    nBase = nt * BN;

  const float* Ap = A + mBase * KDIM;
  const float* Wp = W + ((size_t)e * 512 + nBase) * KDIM;

  // DMA staging: wave w stages rows w*32..w*32+31 of both A and W.
  // One gload16 covers 8 rows x 8 granules; 4 per matrix per wave per tile.
  const int srow8 = lane >> 3;   // row within 8-row chunk
  const int sg    = lane & 7;    // granule within row

#define STAGE(T, buf)                                                        \
  {                                                                          \
    _Pragma("unroll")                                                        \
    for (int i_ = 0; i_ < 4; ++i_) {                                         \
      const int r0_  = wid * 32 + i_ * 8;                                    \
      const int row_ = r0_ + srow8;                                          \
      const int gc_  = (T) * BK + ((sg ^ (row_ & 7)) << 2);                  \
      gload16(Ap + (size_t)row_ * KDIM + gc_, &As[buf][r0_ * BK]);           \
      gload16(Wp + (size_t)row_ * KDIM + gc_, &Ws[buf][r0_ * BK]);           \
    }                                                                        \
  }

  // consume geometry
  const int fr = lane & 15;
  const int q2 = (lane >> 4) << 1;   // granule-pair base: 0,2,4,6

  f32x4 acc[8][4];
  #pragma unroll
  for (int i = 0; i < 8; ++i)
    #pragma unroll
    for (int j = 0; j < 4; ++j)
      acc[i][j] = (f32x4){0.f, 0.f, 0.f, 0.f};

  // ---- prologue: DMA tiles 0,1; wait tile 0 (tile 1 stays in flight) ----
  STAGE(0, 0);
  STAGE(1, 1);
  asm volatile("s_waitcnt vmcnt(8)" ::: "memory");
  __builtin_amdgcn_s_barrier();

  for (int t = 0; t < NT; ++t) {
    const int buf = t & 1;
    const float* Ab = &As[buf][0];
    const float* Wb = &Ws[buf][0];

    // ---- B fragments (4), read fp32 + cvt once per K-tile ----
    bf16x8 bfB[4];
    #pragma unroll
    for (int ni = 0; ni < 4; ++ni) {
      const int r = wn * 64 + ni * 16 + fr;
      const int s = r & 7;
      const f32x4 lo = *(const f32x4*)(Wb + r * BK + ((q2 ^ s) << 2));
      const f32x4 hi = *(const f32x4*)(Wb + r * BK + (((q2 + 1) ^ s) << 2));
      bfB[ni] = cvt8(lo, hi);
    }

    // ---- 4 sub-phases: 2 A-frags + 8 MFMA each; no internal barriers ----
    #pragma unroll
    for (int p = 0; p < 4; ++p) {
      bf16x8 bfA[2];
      #pragma unroll
      for (int u = 0; u < 2; ++u) {
        const int r = wm * 128 + (p * 2 + u) * 16 + fr;
        const int s = r & 7;
        const f32x4 lo = *(const f32x4*)(Ab + r * BK + ((q2 ^ s) << 2));
        const f32x4 hi = *(const f32x4*)(Ab + r * BK + (((q2 + 1) ^ s) << 2));
        bfA[u] = cvt8(lo, hi);
      }
      __builtin_amdgcn_s_setprio(1);
      #pragma unroll
      for (int u = 0; u < 2; ++u)
        #pragma unroll
        for (int ni = 0; ni < 4; ++ni)
          acc[p * 2 + u][ni] = __builtin_amdgcn_mfma_f32_16x16x32_bf16(
              bfA[u], bfB[ni], acc[p * 2 + u][ni], 0, 0, 0);
      __builtin_amdgcn_s_setprio(0);
    }

    // ---- rotate: free buf, DMA tile t+2 into it, then admit tile t+1 ----
    __builtin_amdgcn_sched_barrier(0);
    __builtin_amdgcn_s_barrier();            // all waves done reading buf
    if (t + 2 < NT) STAGE(t + 2, buf);       // DMA into just-freed buffer
    if (t + 1 < NT) {
      if (t + 2 < NT) {
        asm volatile("s_waitcnt vmcnt(8)" ::: "memory");  // t+1 landed; t+2 flying
      } else {
        asm volatile("s_waitcnt vmcnt(0)" ::: "memory");  // last tile
      }
      __builtin_amdgcn_s_barrier();          // t+1 visible to all waves
    }
  }

  // ---- epilogue: C/D layout row = (lane>>4)*4 + reg, col = lane&15 ----
  #pragma unroll
  for (int mi = 0; mi < 8; ++mi) {
    #pragma unroll
    for (int reg = 0; reg < 4; ++reg) {
      const int r = wm * 128 + mi * 16 + ((lane >> 4) << 2) + reg;
      float* rowp = C + (mBase + r) * 512 + nBase + wn * 64 + (lane & 15);
      #pragma unroll
      for (int ni = 0; ni < 4; ++ni)
        __builtin_nontemporal_store(acc[mi][ni][reg], rowp + ni * 16);
    }
  }
#undef STAGE
}

extern "C" void kernel_launch(void* const* d_in, const int* in_sizes, int n_in,
                              void* d_out, int out_size, void* d_ws, size_t ws_size,
                              hipStream_t stream) {
  const float* inputs = (const float*)d_in[0];   // [262144, 512] fp32
  const float* weight = (const float*)d_in[1];   // [8, 512, 512] fp32
  float* out = (float*)d_out;                    // [262144, 512] fp32
  (void)d_ws; (void)ws_size; (void)in_sizes; (void)n_in;

  moe_grouped_gemm<<<2048, 512, 0, stream>>>(inputs, weight, out);
}